// Round 17
// baseline (1716.530 us; speedup 1.0000x reference)
//
#include <hip/hip_runtime.h>

#define EPS 1e-5f
#define SLOPE 0.01f

// ===========================================================================
// Per-ROW sort (conv_up): bin = fine output row (Nf bins).
// rec = dst_down | k<<16   (dst_down < 60000 fits 16 bits, k < 27)
// ===========================================================================
__global__ __launch_bounds__(256) void hist_row(
    const int* __restrict__ scat, int E, int* __restrict__ cnt)
{
    const int k = blockIdx.y;
    const int* s = scat + (size_t)k * E;
    for (int e = blockIdx.x * 256 + threadIdx.x; e < E; e += gridDim.x * 256)
        atomicAdd(&cnt[s[e]], 1);            // avg 5.4 hits per counter
}

__global__ __launch_bounds__(1024) void scan_kernel(
    const int* __restrict__ cnt, int n, int* __restrict__ offs, int* __restrict__ cur)
{
    __shared__ int part[1024];
    const int tid = threadIdx.x;
    const int chunk = (n + 1023) >> 10;
    const int lo = min(n, tid * chunk), hi = min(n, lo + chunk);
    int s = 0;
    for (int i = lo; i < hi; ++i) s += cnt[i];
    part[tid] = s;
    __syncthreads();
    for (int d = 1; d < 1024; d <<= 1) {
        const int t = (tid >= d) ? part[tid - d] : 0;
        __syncthreads();
        part[tid] += t;
        __syncthreads();
    }
    int run = part[tid] - s;
    for (int i = lo; i < hi; ++i) {
        const int cv = cnt[i];
        offs[i] = run; cur[i] = run; run += cv;
    }
    if (tid == 1023) offs[n] = run;
}

__global__ __launch_bounds__(256) void bucket_row(
    const int* __restrict__ gat, const int* __restrict__ scat, int E,
    int* __restrict__ cur, unsigned* __restrict__ recs)
{
    const int k = blockIdx.y;
    const int* g = gat + (size_t)k * E;   // dst_down (coarse value index)
    const int* d = scat + (size_t)k * E;  // src_down (fine row = bin)
    for (int e = blockIdx.x * 256 + threadIdx.x; e < E; e += gridDim.x * 256) {
        const unsigned rec = (unsigned)g[e] | ((unsigned)k << 16);
        const int pos = atomicAdd(&cur[d[e]], 1);
        recs[pos] = rec;
    }
}

// ===========================================================================
// Scatter conv + 8-edge groups + 1-deep register prefetch (R12/R14-verified:
// ~320us phi, 72% VALUBusy). Unchanged.
// ===========================================================================
template<int CHUNKS>
__global__ __launch_bounds__(256) void conv_scatter8(
    const float* __restrict__ x, const float* __restrict__ W,
    const int* __restrict__ src, const int* __restrict__ dst,
    float* __restrict__ acc, int E)
{
    constexpr int CIN = CHUNKS * 64;
    __shared__ float Wl[CIN * 64];      // 16/32 KB
    __shared__ float xl[4][8 * 64];     // 8 KB: per-wave 8 edges x 64-ch chunk
    const int k   = blockIdx.y;
    const int tid = threadIdx.x;
    const int w   = tid >> 6;
    const int c   = tid & 63;

    const float* Wk = W + (size_t)k * (CIN * 64);
    for (int i = tid * 4; i < CIN * 64; i += 1024)
        *(float4*)&Wl[i] = *(const float4*)&Wk[i];
    __syncthreads();

    const int* srcK = src + (size_t)k * E;
    const int* dstK = dst + (size_t)k * E;
    float* xw = xl[w];
    const int stride = gridDim.x * 32;
    const int last = E - 1;

    int e0 = blockIdx.x * 32 + w * 8;
    if (e0 >= E) return;

    int   q[8];
    float g[8][CHUNKS];
    #pragma unroll
    for (int j = 0; j < 8; ++j) q[j] = srcK[min(e0 + j, last)];
    #pragma unroll
    for (int j = 0; j < 8; ++j)
        #pragma unroll
        for (int h = 0; h < CHUNKS; ++h)
            g[j][h] = x[(size_t)q[j] * CIN + h * 64 + c];

    while (e0 < E) {
        const int ne = E - e0;
        int d[8];
        #pragma unroll
        for (int j = 0; j < 8; ++j) d[j] = dstK[min(e0 + j, last)];
        const int en = e0 + stride;

        float a[8] = {0.f, 0.f, 0.f, 0.f, 0.f, 0.f, 0.f, 0.f};
        #pragma unroll
        for (int h = 0; h < CHUNKS; ++h) {
            #pragma unroll
            for (int j = 0; j < 8; ++j)
                xw[j * 64 + c] = g[j][h];
            if (h == CHUNKS - 1 && en < E) {
                #pragma unroll
                for (int j = 0; j < 8; ++j) q[j] = srcK[min(en + j, last)];
                #pragma unroll
                for (int j = 0; j < 8; ++j)
                    #pragma unroll
                    for (int h2 = 0; h2 < CHUNKS; ++h2)
                        g[j][h2] = x[(size_t)q[j] * CIN + h2 * 64 + c];
            }
            __builtin_amdgcn_wave_barrier();

            #pragma unroll 4
            for (int i = 0; i < 64; i += 4) {
                const float w0 = Wl[(h * 64 + i + 0) * 64 + c];
                const float w1 = Wl[(h * 64 + i + 1) * 64 + c];
                const float w2 = Wl[(h * 64 + i + 2) * 64 + c];
                const float w3 = Wl[(h * 64 + i + 3) * 64 + c];
                #pragma unroll
                for (int j = 0; j < 8; ++j) {
                    const float4 xv = *(const float4*)&xw[j * 64 + i];  // broadcast
                    a[j] = fmaf(xv.w, w3, fmaf(xv.z, w2, fmaf(xv.y, w1, fmaf(xv.x, w0, a[j]))));
                }
            }
            __builtin_amdgcn_wave_barrier();
        }

        #pragma unroll
        for (int j = 0; j < 8; ++j)
            if (j < ne) atomicAdd(&acc[(size_t)d[j] * 64 + c], a[j]);
        e0 = en;
    }
}

// ---------------------------------------------------------------------------
// Cin=1 up-conv, ROW-WAVE form: wave = one fine row (lanes = 64 channels).
// Per row: ~5.4 serial edges, each = broadcast rec + broadcast s1 + 1 fma
// into a register. No LDS accumulator, no atomics, no redundant scan.
// One coalesced 256B store per row; fused per-block stats.
// ---------------------------------------------------------------------------
__global__ __launch_bounds__(256) void conv_up_rows(
    const float* __restrict__ s1, const float* __restrict__ Wup,
    const unsigned* __restrict__ recs, const int* __restrict__ offs,
    float* __restrict__ outb, int Nout, float* __restrict__ st)
{
    __shared__ float Wl[27 * 64];            // 6.9 KB
    __shared__ float red[512];               // 2 KB
    const int p   = blockIdx.x;
    const int tid = threadIdx.x;
    const int w   = tid >> 6;
    const int c   = tid & 63;

    for (int i = tid; i < 27 * 64; i += 256) Wl[i] = Wup[i];
    __syncthreads();

    float sSum = 0.f, sSq = 0.f;
    #pragma unroll 1
    for (int rr = 0; rr < 16; ++rr) {
        const int r = p * 64 + rr * 4 + w;
        if (r >= Nout) break;
        const int lo = offs[r], hi = offs[r + 1];
        float acc = 0.f;
        for (int e = lo; e < hi; ++e) {
            const unsigned rec = recs[e];          // broadcast (wave-uniform)
            const float v = s1[rec & 0xFFFFu];     // broadcast
            acc = fmaf(v, Wl[(int)(rec >> 16) * 64 + c], acc);
        }
        outb[(size_t)r * 64 + c] = acc;            // coalesced 256B store
        sSum += acc;
        sSq = fmaf(acc, acc, sSq);
    }

    red[tid] = sSum; red[256 + tid] = sSq;
    __syncthreads();
    if (tid < 64) {
        atomicAdd(&st[c],      red[c] + red[64 + c] + red[128 + c] + red[192 + c]);
        atomicAdd(&st[64 + c], red[256 + c] + red[320 + c] + red[384 + c] + red[448 + c]);
    }
}

// ---------------------------------------------------------------------------
// Cout=1 conv: acc1[dst] += dot(s[src,:64], W_sum[k,:,0]). Thread-per-edge.
// ---------------------------------------------------------------------------
__global__ __launch_bounds__(256) void conv_sum_kernel(
    const float* __restrict__ s, const float* __restrict__ Wsum,
    const int* __restrict__ src, const int* __restrict__ dst,
    float* __restrict__ acc1, int E)
{
    const int k = blockIdx.y;
    __shared__ float Wl[64];
    if (threadIdx.x < 64) Wl[threadIdx.x] = Wsum[k * 64 + threadIdx.x];
    __syncthreads();
    for (int e = blockIdx.x * 256 + threadIdx.x; e < E; e += gridDim.x * 256) {
        const int si = src[(size_t)k * E + e];
        const float4* row = (const float4*)(s + (size_t)si * 64);
        float acc = 0.f;
        #pragma unroll
        for (int q = 0; q < 16; ++q) {
            const float4 v = row[q];
            acc = fmaf(v.x, Wl[q * 4 + 0], acc);
            acc = fmaf(v.y, Wl[q * 4 + 1], acc);
            acc = fmaf(v.z, Wl[q * 4 + 2], acc);
            acc = fmaf(v.w, Wl[q * 4 + 3], acc);
        }
        atomicAdd(&acc1[dst[(size_t)k * E + e]], acc);
    }
}

// ---------------------------------------------------------------------------
// Per-channel (C=64) sum/sumsq. grid.y selects buffer (fused A+B launch).
// ---------------------------------------------------------------------------
__global__ __launch_bounds__(256) void stats64x2(
    const float* __restrict__ xa, const float* __restrict__ xb,
    int N, float* __restrict__ st)   // st: A -> st[0:128], B -> st[128:256]
{
    const float* x = (blockIdx.y == 0) ? xa : xb;
    float* sto = st + (size_t)blockIdx.y * 128;
    const int c  = threadIdx.x & 63;
    const int rg = threadIdx.x >> 6;
    float s = 0.f, q = 0.f;
    for (int r = blockIdx.x * 4 + rg; r < N; r += gridDim.x * 4) {
        const float v = x[(size_t)r * 64 + c];
        s += v;
        q = fmaf(v, v, q);
    }
    __shared__ float ls[256], lq[256];
    ls[threadIdx.x] = s; lq[threadIdx.x] = q;
    __syncthreads();
    if (threadIdx.x < 64) {
        s = ls[c] + ls[64 + c] + ls[128 + c] + ls[192 + c];
        q = lq[c] + lq[64 + c] + lq[128 + c] + lq[192 + c];
        atomicAdd(&sto[c], s);
        atomicAdd(&sto[64 + c], q);
    }
}

__global__ __launch_bounds__(256) void stats64(
    const float* __restrict__ x, int N, float* __restrict__ st)
{
    const int c  = threadIdx.x & 63;
    const int rg = threadIdx.x >> 6;
    float s = 0.f, q = 0.f;
    for (int r = blockIdx.x * 4 + rg; r < N; r += gridDim.x * 4) {
        const float v = x[(size_t)r * 64 + c];
        s += v;
        q = fmaf(v, v, q);
    }
    __shared__ float ls[256], lq[256];
    ls[threadIdx.x] = s; lq[threadIdx.x] = q;
    __syncthreads();
    if (threadIdx.x < 64) {
        s = ls[c] + ls[64 + c] + ls[128 + c] + ls[192 + c];
        q = lq[c] + lq[64 + c] + lq[128 + c] + lq[192 + c];
        atomicAdd(&st[c], s);
        atomicAdd(&st[64 + c], q);
    }
}

__global__ __launch_bounds__(256) void stats1(
    const float* __restrict__ x, int N, float* __restrict__ st)
{
    float s = 0.f, q = 0.f;
    for (int i = blockIdx.x * 256 + threadIdx.x; i < N; i += gridDim.x * 256) {
        const float v = x[i];
        s += v;
        q = fmaf(v, v, q);
    }
    __shared__ float ls[256], lq[256];
    ls[threadIdx.x] = s; lq[threadIdx.x] = q;
    __syncthreads();
    for (int off = 128; off > 0; off >>= 1) {
        if (threadIdx.x < off) {
            ls[threadIdx.x] += ls[threadIdx.x + off];
            lq[threadIdx.x] += lq[threadIdx.x + off];
        }
        __syncthreads();
    }
    if (threadIdx.x == 0) { atomicAdd(&st[0], ls[0]); atomicAdd(&st[1], lq[0]); }
}

// ---------------------------------------------------------------------------
// In-place BN + LeakyReLU on TWO independent buffers (fused A+B launch).
// ---------------------------------------------------------------------------
__global__ __launch_bounds__(256) void apply_bn2(
    float* __restrict__ xa, float* __restrict__ xb,
    const float* __restrict__ st, int N, float invN,
    const float* __restrict__ gamA, const float* __restrict__ betA,
    const float* __restrict__ gamB, const float* __restrict__ betB)
{
    float* x = (blockIdx.y == 0) ? xa : xb;
    const float* stp = st + (size_t)blockIdx.y * 128;
    const float* gam = (blockIdx.y == 0) ? gamA : gamB;
    const float* bet = (blockIdx.y == 0) ? betA : betB;
    __shared__ float sc[64], sh[64];
    if (threadIdx.x < 64) {
        const int c = threadIdx.x;
        const float m = stp[c] * invN;
        const float v = stp[64 + c] * invN - m * m;
        const float s = rsqrtf(v + EPS) * gam[c];
        sc[c] = s;
        sh[c] = bet[c] - m * s;
    }
    __syncthreads();
    const size_t n = (size_t)N * 64;
    for (size_t i = (size_t)blockIdx.x * 256 + threadIdx.x; i < n;
         i += (size_t)gridDim.x * 256) {
        const int c = (int)(i & 63);
        float y = fmaf(x[i], sc[c], sh[c]);
        x[i] = (y >= 0.f) ? y : SLOPE * y;
    }
}

template<int ACT>
__global__ __launch_bounds__(256) void apply_bn(
    float* __restrict__ x, const float* __restrict__ st, int N, float invN,
    const float* __restrict__ gam, const float* __restrict__ bet,
    const float* __restrict__ add)
{
    __shared__ float sc[64], sh[64];
    if (threadIdx.x < 64) {
        const int c = threadIdx.x;
        const float m = st[c] * invN;
        const float v = st[64 + c] * invN - m * m;
        const float s = rsqrtf(v + EPS) * gam[c];
        sc[c] = s;
        sh[c] = bet[c] - m * s;
    }
    __syncthreads();
    const size_t n = (size_t)N * 64;
    for (size_t i = (size_t)blockIdx.x * 256 + threadIdx.x; i < n;
         i += (size_t)gridDim.x * 256) {
        const int c = (int)(i & 63);
        float y = fmaf(x[i], sc[c], sh[c]);
        if (ACT == 0) y = (y >= 0.f) ? y : SLOPE * y;
        else          y = 1.f / (1.f + __expf(-y));
        if (add) y += add[i];
        x[i] = y;
    }
}

__global__ __launch_bounds__(256) void apply_bn1(
    float* __restrict__ x, const float* __restrict__ st, int N, float invN,
    const float* __restrict__ gam, const float* __restrict__ bet)
{
    const float m  = st[0] * invN;
    const float v  = st[1] * invN - m * m;
    const float s  = rsqrtf(v + EPS) * gam[0];
    const float sh = bet[0] - m * s;
    for (int i = blockIdx.x * 256 + threadIdx.x; i < N; i += gridDim.x * 256) {
        const float y = fmaf(x[i], s, sh);
        x[i] = (y >= 0.f) ? y : SLOPE * y;
    }
}

// ---------------------------------------------------------------------------
extern "C" void kernel_launch(void* const* d_in, const int* in_sizes, int n_in,
                              void* d_out, int out_size, void* d_ws, size_t ws_size,
                              hipStream_t stream)
{
    const float* gate     = (const float*)d_in[0];
    const float* shortcut = (const float*)d_in[1];
    const int*   src_down = (const int*)d_in[2];
    const int*   dst_down = (const int*)d_in[3];
    const int*   src_g    = (const int*)d_in[4];
    const int*   dst_g    = (const int*)d_in[5];
    const float* W_sc     = (const float*)d_in[6];
    const float* W_g      = (const float*)d_in[8];
    const float* W_gu     = (const float*)d_in[10];
    const float* W_sum    = (const float*)d_in[12];
    const float* W_up     = (const float*)d_in[13];
    const float* gam_sc   = (const float*)d_in[15];
    const float* bet_sc   = (const float*)d_in[16];
    const float* gam_g    = (const float*)d_in[17];
    const float* bet_g    = (const float*)d_in[18];
    const float* gam_gu   = (const float*)d_in[19];
    const float* bet_gu   = (const float*)d_in[20];
    const float* gam_sum  = (const float*)d_in[21];
    const float* bet_sum  = (const float*)d_in[22];
    const float* gam_up   = (const float*)d_in[23];
    const float* bet_up   = (const float*)d_in[24];

    const int K   = 27;
    const int Nc  = in_sizes[0] / 128;   // 60000
    const int Nf  = in_sizes[1] / 64;    // 200000
    const int Ekd = in_sizes[2] / K;     // 40000
    const int Ekg = in_sizes[4] / K;     // 25000

    float* A  = (float*)d_ws;            // acc_theta -> theta
    float* B  = A + (size_t)Nc * 64;     // acc_phi   -> phi
    float* C  = B + (size_t)Nc * 64;     // acc_phi2  -> s
    float* D  = C + (size_t)Nc * 64;     // acc_s1    -> s1
    float* ST = D + Nc;                  // stats: 640 floats
    int* cnt5 = (int*)(ST + 640);        // Nf ints (zeroed with ws)
    int* off5 = cnt5 + Nf;               // Nf+1
    int* cur5 = off5 + Nf + 1;           // Nf
    unsigned* rec5 = (unsigned*)(cur5 + Nf);    // K*Ekd records (~4.3 MB)

    const size_t zeroBytes = ((size_t)Nc * 64 * 3 + (size_t)Nc + 640) * sizeof(float)
                           + (size_t)Nf * sizeof(int);   // A..D, ST, cnt5
    hipMemsetAsync(d_ws, 0, zeroBytes, stream);
    float* out = (float*)d_out;          // written exactly once by conv_up_rows

    const dim3 blk(256);

    // ---- per-row sort of down-edges (for conv_up) ----
    hist_row<<<dim3(32, K), blk, 0, stream>>>(src_down, Ekd, cnt5);
    scan_kernel<<<1, 1024, 0, stream>>>(cnt5, Nf, off5, cur5);
    bucket_row<<<dim3(64, K), blk, 0, stream>>>(dst_down, src_down, Ekd, cur5, rec5);

    // Grid sizing for whole residency rounds (no straggler round):
    //  CIN=64: 24 KB LDS -> 6 blocks/CU -> 1536 resident; 27*56 = 1512 <= 1536
    //  CIN=128: 40 KB LDS -> 4 blocks/CU -> 1024 resident; 27*75 = 2025 <= 2048
    // theta = leaky(bn(sconv(shortcut, W_sc, src_down->dst_down)))
    conv_scatter8<1><<<dim3(56, K), blk, 0, stream>>>(shortcut, W_sc, src_down, dst_down, A, Ekd);
    // phi_raw = sconv(gate, W_g, src_g->dst_g)
    conv_scatter8<2><<<dim3(75, K), blk, 0, stream>>>(gate, W_g, src_g, dst_g, B, Ekg);

    stats64x2<<<dim3(256, 2), blk, 0, stream>>>(A, B, Nc, ST + 0);
    apply_bn2<<<dim3(1024, 2), blk, 0, stream>>>(A, B, ST + 0, Nc, 1.0f / Nc,
                                                 gam_sc, bet_sc, gam_g, bet_g);

    // phi = leaky(bn(sconv(phi, W_gu, dst_g->src_g)))  (transposed index pairs)
    conv_scatter8<1><<<dim3(56, K), blk, 0, stream>>>(B, W_gu, dst_g, src_g, C, Ekg);
    stats64<<<256, blk, 0, stream>>>(C, Nc, ST + 256);
    // s = leaky(bn(C)) + theta
    apply_bn<0><<<1024, blk, 0, stream>>>(C, ST + 256, Nc, 1.0f / Nc, gam_gu, bet_gu, A);

    // s1 = leaky(bn(sconv(s, W_sum, src_g->dst_g)))   (Cout = 1)
    conv_sum_kernel<<<dim3(32, K), blk, 0, stream>>>(C, W_sum, src_g, dst_g, D, Ekg);
    stats1<<<256, blk, 0, stream>>>(D, Nc, ST + 384);
    apply_bn1<<<256, blk, 0, stream>>>(D, ST + 384, Nc, 1.0f / Nc, gam_sum, bet_sum);

    // out = sigmoid(bn(sconv(s1, W_up, dst_down->src_down)))  (Cin = 1, fine res)
    const int NBR = (Nf + 63) / 64;      // 3125 blocks: wave = one fine row
    conv_up_rows<<<NBR, blk, 0, stream>>>(D, W_up, rec5, off5, out, Nf, ST + 512);
    apply_bn<1><<<2048, blk, 0, stream>>>(out, ST + 512, Nf, 1.0f / Nf, gam_up, bet_up, nullptr);
}

// Round 18
// 1314.315 us; speedup vs baseline: 1.3060x; 1.3060x over previous
//
#include <hip/hip_runtime.h>

#define EPS 1e-5f
#define SLOPE 0.01f

// ===========================================================================
// Per-ROW sort (conv_up): bin = fine output row (Nf bins).
// rec = dst_down | k<<16   (dst_down < 60000 fits 16 bits, k < 27)
// ===========================================================================
__global__ __launch_bounds__(256) void hist_row(
    const int* __restrict__ scat, int E, int* __restrict__ cnt)
{
    const int k = blockIdx.y;
    const int* s = scat + (size_t)k * E;
    for (int e = blockIdx.x * 256 + threadIdx.x; e < E; e += gridDim.x * 256)
        atomicAdd(&cnt[s[e]], 1);            // avg 5.4 hits per counter
}

// ---- hierarchical scan over n bins: p1 tile-reduce, p2 scan partials,
// ---- p3 tile-scan + base. Tiles of 256.
__global__ __launch_bounds__(256) void scan_p1(
    const int* __restrict__ cnt, int n, int* __restrict__ bsum)
{
    __shared__ int sh[256];
    const int i = blockIdx.x * 256 + threadIdx.x;
    sh[threadIdx.x] = (i < n) ? cnt[i] : 0;
    __syncthreads();
    for (int off = 128; off > 0; off >>= 1) {
        if (threadIdx.x < off) sh[threadIdx.x] += sh[threadIdx.x + off];
        __syncthreads();
    }
    if (threadIdx.x == 0) bsum[blockIdx.x] = sh[0];
}

__global__ __launch_bounds__(1024) void scan_p2(
    int* __restrict__ bsum, int nb)
{
    __shared__ int sh[1024];
    const int tid = threadIdx.x;
    const int v = (tid < nb) ? bsum[tid] : 0;
    sh[tid] = v;
    __syncthreads();
    for (int d = 1; d < 1024; d <<= 1) {
        const int t = (tid >= d) ? sh[tid - d] : 0;
        __syncthreads();
        sh[tid] += t;
        __syncthreads();
    }
    if (tid < nb) bsum[tid] = sh[tid] - v;   // exclusive
}

__global__ __launch_bounds__(256) void scan_p3(
    const int* __restrict__ cnt, int n, const int* __restrict__ bsum,
    int* __restrict__ offs, int* __restrict__ cur)
{
    __shared__ int sh[256];
    const int tid = threadIdx.x;
    const int i = blockIdx.x * 256 + tid;
    const int v = (i < n) ? cnt[i] : 0;
    sh[tid] = v;
    __syncthreads();
    for (int d = 1; d < 256; d <<= 1) {
        const int t = (tid >= d) ? sh[tid - d] : 0;
        __syncthreads();
        sh[tid] += t;
        __syncthreads();
    }
    const int base = bsum[blockIdx.x];
    if (i < n) {
        const int ex = base + sh[tid] - v;   // exclusive prefix
        offs[i] = ex;
        cur[i]  = ex;
        if (i == n - 1) offs[n] = base + sh[tid];
    }
}

__global__ __launch_bounds__(256) void bucket_row(
    const int* __restrict__ gat, const int* __restrict__ scat, int E,
    int* __restrict__ cur, unsigned* __restrict__ recs)
{
    const int k = blockIdx.y;
    const int* g = gat + (size_t)k * E;   // dst_down (coarse value index)
    const int* d = scat + (size_t)k * E;  // src_down (fine row = bin)
    for (int e = blockIdx.x * 256 + threadIdx.x; e < E; e += gridDim.x * 256) {
        const unsigned rec = (unsigned)g[e] | ((unsigned)k << 16);
        const int pos = atomicAdd(&cur[d[e]], 1);
        recs[pos] = rec;
    }
}

// ===========================================================================
// Scatter conv + 8-edge groups + 1-deep register prefetch (R12/R14-verified:
// ~320us phi, 72% VALUBusy). Unchanged.
// ===========================================================================
template<int CHUNKS>
__global__ __launch_bounds__(256) void conv_scatter8(
    const float* __restrict__ x, const float* __restrict__ W,
    const int* __restrict__ src, const int* __restrict__ dst,
    float* __restrict__ acc, int E)
{
    constexpr int CIN = CHUNKS * 64;
    __shared__ float Wl[CIN * 64];      // 16/32 KB
    __shared__ float xl[4][8 * 64];     // 8 KB: per-wave 8 edges x 64-ch chunk
    const int k   = blockIdx.y;
    const int tid = threadIdx.x;
    const int w   = tid >> 6;
    const int c   = tid & 63;

    const float* Wk = W + (size_t)k * (CIN * 64);
    for (int i = tid * 4; i < CIN * 64; i += 1024)
        *(float4*)&Wl[i] = *(const float4*)&Wk[i];
    __syncthreads();

    const int* srcK = src + (size_t)k * E;
    const int* dstK = dst + (size_t)k * E;
    float* xw = xl[w];
    const int stride = gridDim.x * 32;
    const int last = E - 1;

    int e0 = blockIdx.x * 32 + w * 8;
    if (e0 >= E) return;

    int   q[8];
    float g[8][CHUNKS];
    #pragma unroll
    for (int j = 0; j < 8; ++j) q[j] = srcK[min(e0 + j, last)];
    #pragma unroll
    for (int j = 0; j < 8; ++j)
        #pragma unroll
        for (int h = 0; h < CHUNKS; ++h)
            g[j][h] = x[(size_t)q[j] * CIN + h * 64 + c];

    while (e0 < E) {
        const int ne = E - e0;
        int d[8];
        #pragma unroll
        for (int j = 0; j < 8; ++j) d[j] = dstK[min(e0 + j, last)];
        const int en = e0 + stride;

        float a[8] = {0.f, 0.f, 0.f, 0.f, 0.f, 0.f, 0.f, 0.f};
        #pragma unroll
        for (int h = 0; h < CHUNKS; ++h) {
            #pragma unroll
            for (int j = 0; j < 8; ++j)
                xw[j * 64 + c] = g[j][h];
            if (h == CHUNKS - 1 && en < E) {
                #pragma unroll
                for (int j = 0; j < 8; ++j) q[j] = srcK[min(en + j, last)];
                #pragma unroll
                for (int j = 0; j < 8; ++j)
                    #pragma unroll
                    for (int h2 = 0; h2 < CHUNKS; ++h2)
                        g[j][h2] = x[(size_t)q[j] * CIN + h2 * 64 + c];
            }
            __builtin_amdgcn_wave_barrier();

            #pragma unroll 4
            for (int i = 0; i < 64; i += 4) {
                const float w0 = Wl[(h * 64 + i + 0) * 64 + c];
                const float w1 = Wl[(h * 64 + i + 1) * 64 + c];
                const float w2 = Wl[(h * 64 + i + 2) * 64 + c];
                const float w3 = Wl[(h * 64 + i + 3) * 64 + c];
                #pragma unroll
                for (int j = 0; j < 8; ++j) {
                    const float4 xv = *(const float4*)&xw[j * 64 + i];  // broadcast
                    a[j] = fmaf(xv.w, w3, fmaf(xv.z, w2, fmaf(xv.y, w1, fmaf(xv.x, w0, a[j]))));
                }
            }
            __builtin_amdgcn_wave_barrier();
        }

        #pragma unroll
        for (int j = 0; j < 8; ++j)
            if (j < ne) atomicAdd(&acc[(size_t)d[j] * 64 + c], a[j]);
        e0 = en;
    }
}

// ---------------------------------------------------------------------------
// Cin=1 up-conv, ROW-WAVE form (R17-validated structure): wave = one fine
// row (lanes = 64 channels); ~5.4 serial edges/row, broadcast loads, one
// register accumulator, no atomics, one coalesced 256B store per row.
// ---------------------------------------------------------------------------
__global__ __launch_bounds__(256) void conv_up_rows(
    const float* __restrict__ s1, const float* __restrict__ Wup,
    const unsigned* __restrict__ recs, const int* __restrict__ offs,
    float* __restrict__ outb, int Nout, float* __restrict__ st)
{
    __shared__ float Wl[27 * 64];            // 6.9 KB
    __shared__ float red[512];               // 2 KB
    const int p   = blockIdx.x;
    const int tid = threadIdx.x;
    const int w   = tid >> 6;
    const int c   = tid & 63;

    for (int i = tid; i < 27 * 64; i += 256) Wl[i] = Wup[i];
    __syncthreads();

    float sSum = 0.f, sSq = 0.f;
    #pragma unroll 1
    for (int rr = 0; rr < 16; ++rr) {
        const int r = p * 64 + rr * 4 + w;
        if (r >= Nout) break;
        const int lo = offs[r], hi = offs[r + 1];
        float acc = 0.f;
        for (int e = lo; e < hi; ++e) {
            const unsigned rec = recs[e];          // broadcast (wave-uniform)
            const float v = s1[rec & 0xFFFFu];     // broadcast
            acc = fmaf(v, Wl[(int)(rec >> 16) * 64 + c], acc);
        }
        outb[(size_t)r * 64 + c] = acc;            // coalesced 256B store
        sSum += acc;
        sSq = fmaf(acc, acc, sSq);
    }

    red[tid] = sSum; red[256 + tid] = sSq;
    __syncthreads();
    if (tid < 64) {
        atomicAdd(&st[c],      red[c] + red[64 + c] + red[128 + c] + red[192 + c]);
        atomicAdd(&st[64 + c], red[256 + c] + red[320 + c] + red[384 + c] + red[448 + c]);
    }
}

// ---------------------------------------------------------------------------
// Cout=1 conv: acc1[dst] += dot(s[src,:64], W_sum[k,:,0]). Thread-per-edge.
// ---------------------------------------------------------------------------
__global__ __launch_bounds__(256) void conv_sum_kernel(
    const float* __restrict__ s, const float* __restrict__ Wsum,
    const int* __restrict__ src, const int* __restrict__ dst,
    float* __restrict__ acc1, int E)
{
    const int k = blockIdx.y;
    __shared__ float Wl[64];
    if (threadIdx.x < 64) Wl[threadIdx.x] = Wsum[k * 64 + threadIdx.x];
    __syncthreads();
    for (int e = blockIdx.x * 256 + threadIdx.x; e < E; e += gridDim.x * 256) {
        const int si = src[(size_t)k * E + e];
        const float4* row = (const float4*)(s + (size_t)si * 64);
        float acc = 0.f;
        #pragma unroll
        for (int q = 0; q < 16; ++q) {
            const float4 v = row[q];
            acc = fmaf(v.x, Wl[q * 4 + 0], acc);
            acc = fmaf(v.y, Wl[q * 4 + 1], acc);
            acc = fmaf(v.z, Wl[q * 4 + 2], acc);
            acc = fmaf(v.w, Wl[q * 4 + 3], acc);
        }
        atomicAdd(&acc1[dst[(size_t)k * E + e]], acc);
    }
}

// ---------------------------------------------------------------------------
// Per-channel (C=64) sum/sumsq. grid.y selects buffer (fused A+B launch).
// ---------------------------------------------------------------------------
__global__ __launch_bounds__(256) void stats64x2(
    const float* __restrict__ xa, const float* __restrict__ xb,
    int N, float* __restrict__ st)   // st: A -> st[0:128], B -> st[128:256]
{
    const float* x = (blockIdx.y == 0) ? xa : xb;
    float* sto = st + (size_t)blockIdx.y * 128;
    const int c  = threadIdx.x & 63;
    const int rg = threadIdx.x >> 6;
    float s = 0.f, q = 0.f;
    for (int r = blockIdx.x * 4 + rg; r < N; r += gridDim.x * 4) {
        const float v = x[(size_t)r * 64 + c];
        s += v;
        q = fmaf(v, v, q);
    }
    __shared__ float ls[256], lq[256];
    ls[threadIdx.x] = s; lq[threadIdx.x] = q;
    __syncthreads();
    if (threadIdx.x < 64) {
        s = ls[c] + ls[64 + c] + ls[128 + c] + ls[192 + c];
        q = lq[c] + lq[64 + c] + lq[128 + c] + lq[192 + c];
        atomicAdd(&sto[c], s);
        atomicAdd(&sto[64 + c], q);
    }
}

__global__ __launch_bounds__(256) void stats64(
    const float* __restrict__ x, int N, float* __restrict__ st)
{
    const int c  = threadIdx.x & 63;
    const int rg = threadIdx.x >> 6;
    float s = 0.f, q = 0.f;
    for (int r = blockIdx.x * 4 + rg; r < N; r += gridDim.x * 4) {
        const float v = x[(size_t)r * 64 + c];
        s += v;
        q = fmaf(v, v, q);
    }
    __shared__ float ls[256], lq[256];
    ls[threadIdx.x] = s; lq[threadIdx.x] = q;
    __syncthreads();
    if (threadIdx.x < 64) {
        s = ls[c] + ls[64 + c] + ls[128 + c] + ls[192 + c];
        q = lq[c] + lq[64 + c] + lq[128 + c] + lq[192 + c];
        atomicAdd(&st[c], s);
        atomicAdd(&st[64 + c], q);
    }
}

__global__ __launch_bounds__(256) void stats1(
    const float* __restrict__ x, int N, float* __restrict__ st)
{
    float s = 0.f, q = 0.f;
    for (int i = blockIdx.x * 256 + threadIdx.x; i < N; i += gridDim.x * 256) {
        const float v = x[i];
        s += v;
        q = fmaf(v, v, q);
    }
    __shared__ float ls[256], lq[256];
    ls[threadIdx.x] = s; lq[threadIdx.x] = q;
    __syncthreads();
    for (int off = 128; off > 0; off >>= 1) {
        if (threadIdx.x < off) {
            ls[threadIdx.x] += ls[threadIdx.x + off];
            lq[threadIdx.x] += lq[threadIdx.x + off];
        }
        __syncthreads();
    }
    if (threadIdx.x == 0) { atomicAdd(&st[0], ls[0]); atomicAdd(&st[1], lq[0]); }
}

// ---------------------------------------------------------------------------
// In-place BN + LeakyReLU on TWO independent buffers (fused A+B launch).
// ---------------------------------------------------------------------------
__global__ __launch_bounds__(256) void apply_bn2(
    float* __restrict__ xa, float* __restrict__ xb,
    const float* __restrict__ st, int N, float invN,
    const float* __restrict__ gamA, const float* __restrict__ betA,
    const float* __restrict__ gamB, const float* __restrict__ betB)
{
    float* x = (blockIdx.y == 0) ? xa : xb;
    const float* stp = st + (size_t)blockIdx.y * 128;
    const float* gam = (blockIdx.y == 0) ? gamA : gamB;
    const float* bet = (blockIdx.y == 0) ? betA : betB;
    __shared__ float sc[64], sh[64];
    if (threadIdx.x < 64) {
        const int c = threadIdx.x;
        const float m = stp[c] * invN;
        const float v = stp[64 + c] * invN - m * m;
        const float s = rsqrtf(v + EPS) * gam[c];
        sc[c] = s;
        sh[c] = bet[c] - m * s;
    }
    __syncthreads();
    const size_t n = (size_t)N * 64;
    for (size_t i = (size_t)blockIdx.x * 256 + threadIdx.x; i < n;
         i += (size_t)gridDim.x * 256) {
        const int c = (int)(i & 63);
        float y = fmaf(x[i], sc[c], sh[c]);
        x[i] = (y >= 0.f) ? y : SLOPE * y;
    }
}

template<int ACT>
__global__ __launch_bounds__(256) void apply_bn(
    float* __restrict__ x, const float* __restrict__ st, int N, float invN,
    const float* __restrict__ gam, const float* __restrict__ bet,
    const float* __restrict__ add)
{
    __shared__ float sc[64], sh[64];
    if (threadIdx.x < 64) {
        const int c = threadIdx.x;
        const float m = st[c] * invN;
        const float v = st[64 + c] * invN - m * m;
        const float s = rsqrtf(v + EPS) * gam[c];
        sc[c] = s;
        sh[c] = bet[c] - m * s;
    }
    __syncthreads();
    const size_t n = (size_t)N * 64;
    for (size_t i = (size_t)blockIdx.x * 256 + threadIdx.x; i < n;
         i += (size_t)gridDim.x * 256) {
        const int c = (int)(i & 63);
        float y = fmaf(x[i], sc[c], sh[c]);
        if (ACT == 0) y = (y >= 0.f) ? y : SLOPE * y;
        else          y = 1.f / (1.f + __expf(-y));
        if (add) y += add[i];
        x[i] = y;
    }
}

__global__ __launch_bounds__(256) void apply_bn1(
    float* __restrict__ x, const float* __restrict__ st, int N, float invN,
    const float* __restrict__ gam, const float* __restrict__ bet)
{
    const float m  = st[0] * invN;
    const float v  = st[1] * invN - m * m;
    const float s  = rsqrtf(v + EPS) * gam[0];
    const float sh = bet[0] - m * s;
    for (int i = blockIdx.x * 256 + threadIdx.x; i < N; i += gridDim.x * 256) {
        const float y = fmaf(x[i], s, sh);
        x[i] = (y >= 0.f) ? y : SLOPE * y;
    }
}

// ---------------------------------------------------------------------------
extern "C" void kernel_launch(void* const* d_in, const int* in_sizes, int n_in,
                              void* d_out, int out_size, void* d_ws, size_t ws_size,
                              hipStream_t stream)
{
    const float* gate     = (const float*)d_in[0];
    const float* shortcut = (const float*)d_in[1];
    const int*   src_down = (const int*)d_in[2];
    const int*   dst_down = (const int*)d_in[3];
    const int*   src_g    = (const int*)d_in[4];
    const int*   dst_g    = (const int*)d_in[5];
    const float* W_sc     = (const float*)d_in[6];
    const float* W_g      = (const float*)d_in[8];
    const float* W_gu     = (const float*)d_in[10];
    const float* W_sum    = (const float*)d_in[12];
    const float* W_up     = (const float*)d_in[13];
    const float* gam_sc   = (const float*)d_in[15];
    const float* bet_sc   = (const float*)d_in[16];
    const float* gam_g    = (const float*)d_in[17];
    const float* bet_g    = (const float*)d_in[18];
    const float* gam_gu   = (const float*)d_in[19];
    const float* bet_gu   = (const float*)d_in[20];
    const float* gam_sum  = (const float*)d_in[21];
    const float* bet_sum  = (const float*)d_in[22];
    const float* gam_up   = (const float*)d_in[23];
    const float* bet_up   = (const float*)d_in[24];

    const int K   = 27;
    const int Nc  = in_sizes[0] / 128;   // 60000
    const int Nf  = in_sizes[1] / 64;    // 200000
    const int Ekd = in_sizes[2] / K;     // 40000
    const int Ekg = in_sizes[4] / K;     // 25000

    const int NBS = (Nf + 255) / 256;    // 782 scan tiles

    float* A  = (float*)d_ws;            // acc_theta -> theta
    float* B  = A + (size_t)Nc * 64;     // acc_phi   -> phi
    float* C  = B + (size_t)Nc * 64;     // acc_phi2  -> s
    float* D  = C + (size_t)Nc * 64;     // acc_s1    -> s1
    float* ST = D + Nc;                  // stats: 640 floats
    int* cnt5 = (int*)(ST + 640);        // Nf ints (zeroed with ws)
    int* off5 = cnt5 + Nf;               // Nf+1
    int* cur5 = off5 + Nf + 1;           // Nf
    int* bsum = cur5 + Nf;               // NBS ints
    unsigned* rec5 = (unsigned*)(bsum + NBS);   // K*Ekd records (~4.3 MB)

    const size_t zeroBytes = ((size_t)Nc * 64 * 3 + (size_t)Nc + 640) * sizeof(float)
                           + (size_t)Nf * sizeof(int);   // A..D, ST, cnt5
    hipMemsetAsync(d_ws, 0, zeroBytes, stream);
    float* out = (float*)d_out;          // written exactly once by conv_up_rows

    const dim3 blk(256);

    // ---- per-row sort of down-edges (for conv_up), parallel 3-pass scan ----
    hist_row<<<dim3(32, K), blk, 0, stream>>>(src_down, Ekd, cnt5);
    scan_p1<<<NBS, blk, 0, stream>>>(cnt5, Nf, bsum);
    scan_p2<<<1, 1024, 0, stream>>>(bsum, NBS);
    scan_p3<<<NBS, blk, 0, stream>>>(cnt5, Nf, bsum, off5, cur5);
    bucket_row<<<dim3(64, K), blk, 0, stream>>>(dst_down, src_down, Ekd, cur5, rec5);

    // Grid sizing for whole residency rounds (no straggler round):
    //  CIN=64: 24 KB LDS -> 6 blocks/CU -> 1536 resident; 27*56 = 1512 <= 1536
    //  CIN=128: 40 KB LDS -> 4 blocks/CU -> 1024 resident; 27*75 = 2025 <= 2048
    // theta = leaky(bn(sconv(shortcut, W_sc, src_down->dst_down)))
    conv_scatter8<1><<<dim3(56, K), blk, 0, stream>>>(shortcut, W_sc, src_down, dst_down, A, Ekd);
    // phi_raw = sconv(gate, W_g, src_g->dst_g)
    conv_scatter8<2><<<dim3(75, K), blk, 0, stream>>>(gate, W_g, src_g, dst_g, B, Ekg);

    stats64x2<<<dim3(256, 2), blk, 0, stream>>>(A, B, Nc, ST + 0);
    apply_bn2<<<dim3(1024, 2), blk, 0, stream>>>(A, B, ST + 0, Nc, 1.0f / Nc,
                                                 gam_sc, bet_sc, gam_g, bet_g);

    // phi = leaky(bn(sconv(phi, W_gu, dst_g->src_g)))  (transposed index pairs)
    conv_scatter8<1><<<dim3(56, K), blk, 0, stream>>>(B, W_gu, dst_g, src_g, C, Ekg);
    stats64<<<256, blk, 0, stream>>>(C, Nc, ST + 256);
    // s = leaky(bn(C)) + theta
    apply_bn<0><<<1024, blk, 0, stream>>>(C, ST + 256, Nc, 1.0f / Nc, gam_gu, bet_gu, A);

    // s1 = leaky(bn(sconv(s, W_sum, src_g->dst_g)))   (Cout = 1)
    conv_sum_kernel<<<dim3(32, K), blk, 0, stream>>>(C, W_sum, src_g, dst_g, D, Ekg);
    stats1<<<256, blk, 0, stream>>>(D, Nc, ST + 384);
    apply_bn1<<<256, blk, 0, stream>>>(D, ST + 384, Nc, 1.0f / Nc, gam_sum, bet_sum);

    // out = sigmoid(bn(sconv(s1, W_up, dst_down->src_down)))  (Cin = 1, fine res)
    const int NBR = (Nf + 63) / 64;      // 3125 blocks: wave = one fine row
    conv_up_rows<<<NBR, blk, 0, stream>>>(D, W_up, rec5, off5, out, Nf, ST + 512);
    apply_bn<1><<<2048, blk, 0, stream>>>(out, ST + 512, Nf, 1.0f / Nf, gam_up, bet_up, nullptr);
}